// Round 11
// baseline (925.984 us; speedup 1.0000x reference)
//
#include <hip/hip_runtime.h>
#include <hip/hip_fp16.h>
#include <math.h>

#define N_NODES 50000
#define N_EDGES 800000
#define NB 256
#define AD 39
#define BD 10
#define H 128
#define HQ 64
#define HEADS 4
#define HD 32
#define LAYERS 3
#define TD 128

__device__ __forceinline__ float silu_f(float x) { return x / (1.f + __expf(-x)); }

// ---------------------------------------------------------------------------
// Specialized GEMM: out[N,128] = act(A[N,KT] @ W[KT,128](ldw) + bias
//                                    + bias2[gidx[n]])
// Optional fused attention scores: outS/outD[n][head] = sum_c out[n][c]*att[c]
// ---------------------------------------------------------------------------
__device__ __forceinline__ void fma_rank1(float acc[8][4], float4 aL, float4 aH, float4 w)
{
    float ar[8] = {aL.x, aL.y, aL.z, aL.w, aH.x, aH.y, aH.z, aH.w};
    float wr[4] = {w.x, w.y, w.z, w.w};
#pragma unroll
    for (int r = 0; r < 8; r++)
#pragma unroll
        for (int j = 0; j < 4; j++) acc[r][j] += ar[r] * wr[j];
}

template<int KT>
__global__ __launch_bounds__(256) void gemm128(
    const float* __restrict__ A, const float* __restrict__ W,
    const float* __restrict__ bias, const float* __restrict__ bias2,
    const int* __restrict__ gidx, float* __restrict__ out,
    int Nrows, int ldw, int act,
    const float* __restrict__ attS, const float* __restrict__ attD,
    float* __restrict__ outS, float* __restrict__ outD)
{
    __shared__ float As[KT * 68];
    const int tid = threadIdx.x;
    const int rowBase = blockIdx.x * 64;

    for (int idx = tid; idx < 64 * KT; idx += 256) {
        int row = idx / KT;
        int k = idx - row * KT;
        int n = rowBase + row;
        As[k * 68 + row] = (n < Nrows) ? A[(size_t)n * KT + k] : 0.f;
    }
    __syncthreads();

    const int c0 = (tid & 31) * 4;
    const int n0 = (tid >> 5) * 8;

    float acc[8][4];
#pragma unroll
    for (int r = 0; r < 8; r++)
#pragma unroll
        for (int j = 0; j < 4; j++) acc[r][j] = 0.f;

    const float* wp = W + c0;
    int k = 0;
    for (; k + 4 <= KT; k += 4) {
        float4 w0 = *(const float4*)&wp[(size_t)(k + 0) * ldw];
        float4 w1 = *(const float4*)&wp[(size_t)(k + 1) * ldw];
        float4 w2 = *(const float4*)&wp[(size_t)(k + 2) * ldw];
        float4 w3 = *(const float4*)&wp[(size_t)(k + 3) * ldw];
        float4 aL0 = *(const float4*)&As[(k + 0) * 68 + n0];
        float4 aH0 = *(const float4*)&As[(k + 0) * 68 + n0 + 4];
        float4 aL1 = *(const float4*)&As[(k + 1) * 68 + n0];
        float4 aH1 = *(const float4*)&As[(k + 1) * 68 + n0 + 4];
        float4 aL2 = *(const float4*)&As[(k + 2) * 68 + n0];
        float4 aH2 = *(const float4*)&As[(k + 2) * 68 + n0 + 4];
        float4 aL3 = *(const float4*)&As[(k + 3) * 68 + n0];
        float4 aH3 = *(const float4*)&As[(k + 3) * 68 + n0 + 4];
        fma_rank1(acc, aL0, aH0, w0);
        fma_rank1(acc, aL1, aH1, w1);
        fma_rank1(acc, aL2, aH2, w2);
        fma_rank1(acc, aL3, aH3, w3);
    }
    for (; k < KT; ++k) {
        float4 w0 = *(const float4*)&wp[(size_t)k * ldw];
        float4 aL = *(const float4*)&As[k * 68 + n0];
        float4 aH = *(const float4*)&As[k * 68 + n0 + 4];
        fma_rank1(acc, aL, aH, w0);
    }

    float4 bv = make_float4(0.f, 0.f, 0.f, 0.f);
    if (bias) bv = *(const float4*)&bias[c0];
    float4 aSv = make_float4(0.f, 0.f, 0.f, 0.f);
    float4 aDv = make_float4(0.f, 0.f, 0.f, 0.f);
    if (outS) { aSv = *(const float4*)&attS[c0]; aDv = *(const float4*)&attD[c0]; }

#pragma unroll
    for (int r = 0; r < 8; r++) {
        int n = rowBase + n0 + r;
        if (n >= Nrows) break;   // uniform within each 32-lane group
        float4 o;
        o.x = acc[r][0] + bv.x;
        o.y = acc[r][1] + bv.y;
        o.z = acc[r][2] + bv.z;
        o.w = acc[r][3] + bv.w;
        if (bias2) {
            float4 b2 = *(const float4*)&bias2[(size_t)gidx[n] * H + c0];
            o.x += b2.x; o.y += b2.y; o.z += b2.z; o.w += b2.w;
        }
        if (act) {
            o.x = silu_f(o.x); o.y = silu_f(o.y);
            o.z = silu_f(o.z); o.w = silu_f(o.w);
        }
        *(float4*)&out[(size_t)n * H + c0] = o;
        if (outS) {
            float ps = o.x * aSv.x + o.y * aSv.y + o.z * aSv.z + o.w * aSv.w;
            float pd = o.x * aDv.x + o.y * aDv.y + o.z * aDv.z + o.w * aDv.w;
#pragma unroll
            for (int off = 4; off >= 1; off >>= 1) {
                ps += __shfl_xor(ps, off, 8);
                pd += __shfl_xor(pd, off, 8);
            }
            if ((tid & 7) == 0) {
                int head = (tid & 31) >> 3;
                outS[n * 4 + head] = ps;
                outD[n * 4 + head] = pd;
            }
        }
    }
}

// ---------------------------------------------------------------------------
// Fused noise-prediction head, conflict-free version:
// z1 = silu(nf@W1[0:128] + tgW[batch]); z2 = silu(z1@W2 + b2); out = z2@W3+b3.
// A staged ROW-MAJOR As[row][132]; GEMM A-reads are half-wave broadcasts
// (n0 uniform per 32-lane group); inter-stage writes are lane-sequential
// float4 (conflict-free).  No transpose anywhere.
// ---------------------------------------------------------------------------
#define S2 132
__global__ __launch_bounds__(256) void np_fused(
    const float* __restrict__ nf, const int* __restrict__ batch,
    const float* __restrict__ tgW,
    const float* __restrict__ npW1,
    const float* __restrict__ npW2, const float* __restrict__ npb2,
    const float* __restrict__ npW3, const float* __restrict__ npb3,
    float* __restrict__ out, int Nrows)
{
    __shared__ float As[64 * S2];
    const int tid = threadIdx.x;
    const int rowBase = blockIdx.x * 64;
    const int c0 = (tid & 31) * 4;
    const int n0 = (tid >> 5) * 8;   // uniform per 32-lane group

    // straight row-major copy (coalesced global, sequential LDS)
    for (int idx = tid; idx < 64 * H; idx += 256) {
        int row = idx >> 7;
        int k = idx & 127;
        int n = rowBase + row;
        As[row * S2 + k] = (n < Nrows) ? nf[(size_t)n * H + k] : 0.f;
    }
    __syncthreads();

    float acc[8][4];

    // ---- GEMM1: z1 = nf @ W1 (broadcast A-reads) ----
#pragma unroll
    for (int r = 0; r < 8; r++)
#pragma unroll
        for (int j = 0; j < 4; j++) acc[r][j] = 0.f;
    {
        const float* wp = npW1 + c0;
        for (int k = 0; k < H; k += 4) {
            float4 w0 = *(const float4*)&wp[(size_t)(k + 0) * H];
            float4 w1 = *(const float4*)&wp[(size_t)(k + 1) * H];
            float4 w2 = *(const float4*)&wp[(size_t)(k + 2) * H];
            float4 w3 = *(const float4*)&wp[(size_t)(k + 3) * H];
#pragma unroll
            for (int r = 0; r < 8; r++) {
                float4 a = *(const float4*)&As[(n0 + r) * S2 + k];  // broadcast
                acc[r][0] += a.x * w0.x + a.y * w1.x + a.z * w2.x + a.w * w3.x;
                acc[r][1] += a.x * w0.y + a.y * w1.y + a.z * w2.y + a.w * w3.y;
                acc[r][2] += a.x * w0.z + a.y * w1.z + a.z * w2.z + a.w * w3.z;
                acc[r][3] += a.x * w0.w + a.y * w1.w + a.z * w2.w + a.w * w3.w;
            }
        }
    }
    __syncthreads();  // all GEMM1 reads done before overwrite
#pragma unroll
    for (int r = 0; r < 8; r++) {
        int n = rowBase + n0 + r;
        float4 tg = make_float4(0.f, 0.f, 0.f, 0.f);
        if (n < Nrows) tg = *(const float4*)&tgW[(size_t)batch[n] * H + c0];
        float4 v;
        v.x = silu_f(acc[r][0] + tg.x);
        v.y = silu_f(acc[r][1] + tg.y);
        v.z = silu_f(acc[r][2] + tg.z);
        v.w = silu_f(acc[r][3] + tg.w);
        *(float4*)&As[(n0 + r) * S2 + c0] = v;   // lane-sequential, conflict-free
    }
    __syncthreads();

    // ---- GEMM2: z2 = z1 @ W2 ----
#pragma unroll
    for (int r = 0; r < 8; r++)
#pragma unroll
        for (int j = 0; j < 4; j++) acc[r][j] = 0.f;
    {
        const float* wp = npW2 + c0;
        for (int k = 0; k < H; k += 4) {
            float4 w0 = *(const float4*)&wp[(size_t)(k + 0) * H];
            float4 w1 = *(const float4*)&wp[(size_t)(k + 1) * H];
            float4 w2 = *(const float4*)&wp[(size_t)(k + 2) * H];
            float4 w3 = *(const float4*)&wp[(size_t)(k + 3) * H];
#pragma unroll
            for (int r = 0; r < 8; r++) {
                float4 a = *(const float4*)&As[(n0 + r) * S2 + k];
                acc[r][0] += a.x * w0.x + a.y * w1.x + a.z * w2.x + a.w * w3.x;
                acc[r][1] += a.x * w0.y + a.y * w1.y + a.z * w2.y + a.w * w3.y;
                acc[r][2] += a.x * w0.z + a.y * w1.z + a.z * w2.z + a.w * w3.z;
                acc[r][3] += a.x * w0.w + a.y * w1.w + a.z * w2.w + a.w * w3.w;
            }
        }
    }
    __syncthreads();
    {
        float4 b2 = *(const float4*)&npb2[c0];
#pragma unroll
        for (int r = 0; r < 8; r++) {
            float4 v;
            v.x = silu_f(acc[r][0] + b2.x);
            v.y = silu_f(acc[r][1] + b2.y);
            v.z = silu_f(acc[r][2] + b2.z);
            v.w = silu_f(acc[r][3] + b2.w);
            *(float4*)&As[(n0 + r) * S2 + c0] = v;
        }
    }
    __syncthreads();

    // ---- GEMM3: out[64,39] = z2 @ W3 + b3 ----
    // half-wave hw owns rows hw*8..hw*8+7; lane owns cols {l, l+32 if <39}.
    {
        int l = tid & 31;
        int row0 = n0;               // same 8-row group as before
        bool two = (l + 32 < AD);
        float a0[8], a1[8];
#pragma unroll
        for (int r = 0; r < 8; r++) { a0[r] = 0.f; a1[r] = 0.f; }
        for (int k = 0; k < H; k += 4) {
            float4 av[8];
#pragma unroll
            for (int r = 0; r < 8; r++)
                av[r] = *(const float4*)&As[(row0 + r) * S2 + k];  // broadcast
#pragma unroll
            for (int kk = 0; kk < 4; kk++) {
                float w0 = npW3[(size_t)(k + kk) * AD + l];
                float w1 = two ? npW3[(size_t)(k + kk) * AD + l + 32] : 0.f;
                float* avf = (float*)&av[0];
#pragma unroll
                for (int r = 0; r < 8; r++) {
                    float a = ((const float*)&av[r])[kk];
                    a0[r] += a * w0;
                    a1[r] += a * w1;
                }
                (void)avf;
            }
        }
        float b0 = npb3[l];
        float b1 = two ? npb3[l + 32] : 0.f;
#pragma unroll
        for (int r = 0; r < 8; r++) {
            int n = rowBase + row0 + r;
            if (n >= Nrows) break;
            out[(size_t)n * AD + l] = a0[r] + b0;
            if (two) out[(size_t)n * AD + l + 32] = a1[r] + b1;
        }
    }
}

// ---------------------------------------------------------------------------
// Fold edge path coefficients
// ---------------------------------------------------------------------------
__global__ __launch_bounds__(256) void precompute_small(
    const float* __restrict__ edge_W, const float* __restrict__ att_edge,
    const float* __restrict__ bond_W, const float* __restrict__ bond_b,
    float* __restrict__ mc)
{
    __shared__ float bl[LAYERS][H][4];
    int tid = threadIdx.x;
    for (int task = tid; task < LAYERS * H; task += 256) {
        int l = task / H, k = task % H;
#pragma unroll
        for (int hh = 0; hh < 4; hh++) {
            float s = 0.f;
            for (int d = 0; d < HD; d++)
                s += edge_W[(size_t)l * H * H + k * H + hh * HD + d] *
                     att_edge[l * H + hh * HD + d];
            bl[l][k][hh] = s;
        }
    }
    __syncthreads();
    if (tid < LAYERS * BD * 4) {
        int l = tid / (BD * 4), r = tid % (BD * 4), j = r / 4, hh = r % 4;
        float s = 0.f;
        for (int k = 0; k < H; k++) s += bond_W[j * H + k] * bl[l][k][hh];
        mc[l * 44 + j * 4 + hh] = s;
    }
    if (tid >= 128 && tid < 128 + LAYERS * 4) {
        int r = tid - 128, l = r / 4, hh = r % 4;
        float s = 0.f;
        for (int k = 0; k < H; k++) s += bond_b[k] * bl[l][k][hh];
        mc[l * 44 + 40 + hh] = s;
    }
}

// ---------------------------------------------------------------------------
__global__ __launch_bounds__(128) void time_embed(
    const int* __restrict__ t,
    const float* __restrict__ W1, const float* __restrict__ b1,
    const float* __restrict__ W2, const float* __restrict__ b2,
    float* __restrict__ t_emb)
{
    int g = blockIdx.x, c = threadIdx.x;
    float tf = (float)t[g];
    __shared__ float emb[TD], z[H];
    int k = c & 63;
    float f = __expf(-9.210340371976184f * (float)k / 63.0f);
    float e = tf * f;
    emb[c] = (c < 64) ? sinf(e) : cosf(e);
    __syncthreads();
    float a1 = b1[c];
    for (int kk = 0; kk < TD; kk++) a1 += emb[kk] * W1[kk * H + c];
    z[c] = silu_f(a1);
    __syncthreads();
    float a2 = b2[c];
    for (int kk = 0; kk < H; kk++) a2 += z[kk] * W2[kk * H + c];
    t_emb[g * H + c] = a2;
}

// ---------------------------------------------------------------------------
// CSR build
// ---------------------------------------------------------------------------
__global__ __launch_bounds__(256) void hist_dst(const int* __restrict__ edge_index,
                                                int* __restrict__ deg)
{
    int e = blockIdx.x * 256 + threadIdx.x;
    if (e < N_EDGES) atomicAdd(&deg[edge_index[N_EDGES + e]], 1);
}

__global__ __launch_bounds__(320) void gptr_bsearch(const int* __restrict__ batch,
                                                    int* __restrict__ gptr)
{
    int g = threadIdx.x;
    if (g > NB) return;
    int lo = 0, hi = N_NODES;
    while (lo < hi) {
        int mid = (lo + hi) >> 1;
        if (batch[mid] < g) lo = mid + 1; else hi = mid;
    }
    gptr[g] = lo;
}

__global__ __launch_bounds__(256) void scan_part(const int* __restrict__ cnt,
                                                 int* __restrict__ bsum, int n)
{
    int tid = threadIdx.x;
    int i0 = blockIdx.x * 1024 + tid * 4;
    int s = 0;
#pragma unroll
    for (int j = 0; j < 4; j++) if (i0 + j < n) s += cnt[i0 + j];
    __shared__ int red[256];
    red[tid] = s;
    __syncthreads();
    for (int off = 128; off >= 1; off >>= 1) {
        if (tid < off) red[tid] += red[tid + off];
        __syncthreads();
    }
    if (tid == 0) bsum[blockIdx.x] = red[0];
}

__global__ __launch_bounds__(256) void scan_tops(const int* __restrict__ bsum,
                                                 int* __restrict__ boff, int G,
                                                 int* __restrict__ total)
{
    int tid = threadIdx.x;
    int v = (tid < G) ? bsum[tid] : 0;
    __shared__ int ps[256];
    ps[tid] = v;
    __syncthreads();
    for (int off = 1; off < 256; off <<= 1) {
        int t = (tid >= off) ? ps[tid - off] : 0;
        __syncthreads();
        ps[tid] += t;
        __syncthreads();
    }
    if (tid < G) boff[tid] = ps[tid] - v;
    if (tid == 255) *total = ps[255];
}

__global__ __launch_bounds__(256) void scan_final(const int* __restrict__ cnt,
                                                  const int* __restrict__ boff,
                                                  int* __restrict__ ptr, int n)
{
    int tid = threadIdx.x;
    int i0 = blockIdx.x * 1024 + tid * 4;
    int v[4];
#pragma unroll
    for (int j = 0; j < 4; j++) v[j] = (i0 + j < n) ? cnt[i0 + j] : 0;
    int s = v[0] + v[1] + v[2] + v[3];
    __shared__ int ps[256];
    ps[tid] = s;
    __syncthreads();
    for (int off = 1; off < 256; off <<= 1) {
        int t = (tid >= off) ? ps[tid - off] : 0;
        __syncthreads();
        ps[tid] += t;
        __syncthreads();
    }
    int run = boff[blockIdx.x] + ps[tid] - s;
#pragma unroll
    for (int j = 0; j < 4; j++) {
        if (i0 + j < n) { ptr[i0 + j] = run; run += v[j]; }
    }
}

// One 8B scattered write per edge: csr_se[p] = {src, e}
__global__ __launch_bounds__(256) void scatter_edges(const int* __restrict__ edge_index,
                                                     const int* __restrict__ ptr,
                                                     int* __restrict__ cursor,
                                                     int2* __restrict__ csr_se)
{
    int e = blockIdx.x * 256 + threadIdx.x;
    if (e >= N_EDGES) return;
    int s = edge_index[e];
    int d = edge_index[N_EDGES + e];
    int pos = atomicAdd(&cursor[d], 1);
    csr_se[ptr[d] + pos] = make_int2(s, e);
}

// ---------------------------------------------------------------------------
// ase[p][hh] = sS[src][hh] + edge_attr[e] @ M_l[:,hh] + c_l[hh]  (pre-leaky,
// no dst term).  Gather-based reorder: coalesced p-loop, random READS only,
// coalesced half4 write in CSR order.
// ---------------------------------------------------------------------------
__global__ __launch_bounds__(256) void ase_csr(
    const int2* __restrict__ csr_se, const float* __restrict__ edge_attr,
    const float* __restrict__ sS, const float* __restrict__ mc_l,
    __half* __restrict__ ase)
{
    __shared__ float Ml[BD * 4], cl[4];
    int tid = threadIdx.x;
    if (tid < 40) Ml[tid] = mc_l[tid];
    if (tid >= 40 && tid < 44) cl[tid - 40] = mc_l[tid];
    __syncthreads();
    int p = blockIdx.x * 256 + tid;
    if (p >= N_EDGES) return;
    int2 q = csr_se[p];
    float4 ss = *(const float4*)&sS[q.x * 4];
    float s0 = cl[0] + ss.x, s1 = cl[1] + ss.y;
    float s2 = cl[2] + ss.z, s3 = cl[3] + ss.w;
    const float* ea = &edge_attr[(size_t)q.y * BD];
#pragma unroll
    for (int j = 0; j < BD; j++) {
        float x = ea[j];
        s0 += x * Ml[j * 4 + 0]; s1 += x * Ml[j * 4 + 1];
        s2 += x * Ml[j * 4 + 2]; s3 += x * Ml[j * 4 + 3];
    }
    __half2 h01 = __floats2half2_rn(s0, s1);
    __half2 h23 = __floats2half2_rn(s2, s3);
    uint2 u = make_uint2(*(const unsigned*)&h01, *(const unsigned*)&h23);
    *(uint2*)&ase[(size_t)p * 4] = u;
}

// ---------------------------------------------------------------------------
// GAT aggregation for one half: one wave per dst node, online softmax.
// ase (half[E][4], CSR order) streamed; alpha = leaky(ase + sD[n]).
// ---------------------------------------------------------------------------
__global__ __launch_bounds__(256) void gat_agg_h(
    const float* __restrict__ xh, int coff, const __half* __restrict__ ase,
    int hh0, const int* __restrict__ csr_ptr, const int2* __restrict__ csr_se,
    const float* __restrict__ sD,
    const float* __restrict__ conv_b_off, float* __restrict__ agg)
{
    int n = (blockIdx.x * 256 + threadIdx.x) >> 6;
    if (n >= N_NODES) return;
    int lane = threadIdx.x & 63;
    int c = coff + lane;
    int hoff = hh0 + (lane >> 5);
    int start = csr_ptr[n], end = csr_ptr[n + 1];
    float sDn = sD[n * 4 + hoff];

    float m_run = -1e30f, d_run = 0.f, acc = 0.f;

    for (int base = start; base < end; base += 64) {
        int cnt = min(64, end - base);
        int s_l = (lane < cnt) ? csr_se[base + lane].x : 0;
        int i0 = lane & 31;
        float a0 = -1e30f, a1 = -1e30f;
        if (i0 < cnt) {
            float a = __half2float(ase[(size_t)(base + i0) * 4 + hoff]) + sDn;
            a0 = (a >= 0.f) ? a : 0.2f * a;
        }
        if (i0 + 32 < cnt) {
            float a = __half2float(ase[(size_t)(base + i0 + 32) * 4 + hoff]) + sDn;
            a1 = (a >= 0.f) ? a : 0.2f * a;
        }

        float m_blk = fmaxf(a0, a1);
#pragma unroll
        for (int off = 16; off >= 1; off >>= 1)
            m_blk = fmaxf(m_blk, __shfl_xor(m_blk, off, 32));
        float m_new = fmaxf(m_run, m_blk);
        float rescale = __expf(m_run - m_new);
        float e0 = __expf(a0 - m_new);
        float e1 = __expf(a1 - m_new);
        float dsum = e0 + e1;
#pragma unroll
        for (int off = 16; off >= 1; off >>= 1)
            dsum += __shfl_xor(dsum, off, 32);
        d_run = d_run * rescale + dsum;
        acc *= rescale;

        int c1 = min(cnt, 32);
        for (int i = 0; i < c1; i += 4) {
            int s0 = __shfl(s_l, i + 0), s1 = __shfl(s_l, i + 1);
            int s2 = __shfl(s_l, i + 2), s3 = __shfl(s_l, i + 3);
            float w0 = __shfl(e0, i + 0, 32), w1 = __shfl(e0, i + 1, 32);
            float w2 = __shfl(e0, i + 2, 32), w3 = __shfl(e0, i + 3, 32);
            float x0 = xh[(size_t)s0 * H + c];
            float x1 = xh[(size_t)s1 * H + c];
            float x2 = xh[(size_t)s2 * H + c];
            float x3 = xh[(size_t)s3 * H + c];
            acc += x0 * w0 + x1 * w1 + x2 * w2 + x3 * w3;
        }
        for (int i = 32; i < cnt; i += 4) {
            int s0 = __shfl(s_l, i + 0), s1 = __shfl(s_l, i + 1);
            int s2 = __shfl(s_l, i + 2), s3 = __shfl(s_l, i + 3);
            float w0 = __shfl(e1, i - 32, 32), w1 = __shfl(e1, i - 31, 32);
            float w2 = __shfl(e1, i - 30, 32), w3 = __shfl(e1, i - 29, 32);
            float x0 = xh[(size_t)s0 * H + c];
            float x1 = xh[(size_t)s1 * H + c];
            float x2 = xh[(size_t)s2 * H + c];
            float x3 = xh[(size_t)s3 * H + c];
            acc += x0 * w0 + x1 * w1 + x2 * w2 + x3 * w3;
        }
        m_run = m_new;
    }
    float inv = 1.f / (d_run + 1e-16f);
    agg[(size_t)n * HQ + lane] = acc * inv + conv_b_off[lane];
}

// ---------------------------------------------------------------------------
// BatchNorm (per half, 64 channels)
// ---------------------------------------------------------------------------
__global__ __launch_bounds__(256) void bn_partial_h(const float* __restrict__ agg,
                                                    float* __restrict__ part)
{
    __shared__ float red[2][4][64];
    int b = blockIdx.x;
    int c = threadIdx.x & 63;
    int q = threadIdx.x >> 6;
    int per = (N_NODES + 255) / 256;
    int s = b * per, e = min(N_NODES, s + per);
    int qs = s + q * ((per + 3) / 4);
    int qe = min(e, qs + (per + 3) / 4);
    float sum = 0.f, sq = 0.f;
    for (int n = qs; n < qe; n++) {
        float v = agg[(size_t)n * HQ + c];
        sum += v; sq += v * v;
    }
    red[0][q][c] = sum;
    red[1][q][c] = sq;
    __syncthreads();
    if (q == 0) {
        sum = red[0][0][c] + red[0][1][c] + red[0][2][c] + red[0][3][c];
        sq  = red[1][0][c] + red[1][1][c] + red[1][2][c] + red[1][3][c];
        part[b * HQ + c] = sum;
        part[256 * HQ + b * HQ + c] = sq;
    }
}

__global__ __launch_bounds__(256) void bn_finish_h(const float* __restrict__ part,
                                                   const float* __restrict__ gamma,
                                                   const float* __restrict__ beta,
                                                   float* __restrict__ scale,
                                                   float* __restrict__ shift)
{
    __shared__ double red[2][4][64];
    int c = threadIdx.x & 63;
    int g = threadIdx.x >> 6;
    double s = 0.0, q = 0.0;
    for (int b = g * 64; b < (g + 1) * 64; b++) {
        s += (double)part[b * HQ + c];
        q += (double)part[256 * HQ + b * HQ + c];
    }
    red[0][g][c] = s;
    red[1][g][c] = q;
    __syncthreads();
    if (g == 0) {
        s = red[0][0][c] + red[0][1][c] + red[0][2][c] + red[0][3][c];
        q = red[1][0][c] + red[1][1][c] + red[1][2][c] + red[1][3][c];
        float mu = (float)(s / N_NODES);
        float var = (float)(q / N_NODES) - mu * mu;
        float rstd = rsqrtf(var + 1e-5f);
        float sc = gamma[c] * rstd;
        scale[c] = sc;
        shift[c] = beta[c] - mu * sc;
    }
}

__global__ __launch_bounds__(256) void bn_apply_h(const float* __restrict__ agg,
                                                  const float* __restrict__ scale,
                                                  const float* __restrict__ shift,
                                                  float* __restrict__ h, int coff)
{
    int i = blockIdx.x * 256 + threadIdx.x;
    if (i >= N_NODES * HQ / 4) return;
    int n = i >> 4;
    int c0 = (i & 15) * 4;
    float4 v = *(const float4*)&agg[(size_t)n * HQ + c0];
    float4 sc = *(const float4*)&scale[c0];
    float4 sh = *(const float4*)&shift[c0];
    float* hp = &h[(size_t)n * H + coff + c0];
    float4 hv = *(const float4*)hp;
    float4 o;
    o.x = fmaxf(v.x * sc.x + sh.x, 0.f) + hv.x;
    o.y = fmaxf(v.y * sc.y + sh.y, 0.f) + hv.y;
    o.z = fmaxf(v.z * sc.z + sh.z, 0.f) + hv.z;
    o.w = fmaxf(v.w * sc.w + sh.w, 0.f) + hv.w;
    *(float4*)hp = o;
}

// ---------------------------------------------------------------------------
// Graph pooling, stage 1: per-(graph, quarter) partial sums of node features.
// ---------------------------------------------------------------------------
__global__ __launch_bounds__(128) void pool_partial(
    const float* __restrict__ nf, const int* __restrict__ gptr,
    float* __restrict__ pprt)
{
    int g = blockIdx.x >> 2;
    int q = blockIdx.x & 3;
    int c = threadIdx.x;
    int s = gptr[g], e = gptr[g + 1];
    int qlen = (e - s + 3) >> 2;
    int qs = s + q * qlen;
    int qe = min(e, qs + qlen);
    float sum = 0.f;
    for (int n = qs; n < qe; n++) sum += nf[(size_t)n * H + c];
    pprt[((size_t)g * 4 + q) * H + c] = sum;
}

// ---------------------------------------------------------------------------
// Graph head MLP: one 512-thread block per graph.
// ---------------------------------------------------------------------------
__global__ __launch_bounds__(512) void graph_head_mlp(
    const int* __restrict__ gptr, const float* __restrict__ pprt,
    const float* __restrict__ t_emb,
    const float* __restrict__ pW1, const float* __restrict__ pb1,
    const float* __restrict__ pW2, const float* __restrict__ pb2,
    const float* __restrict__ npW1, const float* __restrict__ npb1,
    float* __restrict__ tgW)
{
    int g = blockIdx.x;
    int c = threadIdx.x & 127;
    int q = threadIdx.x >> 7;
    __shared__ float row[H], z[H];
    __shared__ float red[4][H];

    int s = gptr[g], e = gptr[g + 1];
    float cf = (e - s > 0) ? (float)(e - s) : 1.f;
    if (q == 0) {
        row[c] = (pprt[((size_t)g * 4 + 0) * H + c] +
                  pprt[((size_t)g * 4 + 1) * H + c] +
                  pprt[((size_t)g * 4 + 2) * H + c] +
                  pprt[((size_t)g * 4 + 3) * H + c]) / cf;
    }
    __syncthreads();

    float p = 0.f;
#pragma unroll 8
    for (int k = q * 32; k < q * 32 + 32; k++) p += row[k] * pW1[k * H + c];
    red[q][c] = p;
    __syncthreads();
    if (q == 0) z[c] = silu_f(red[0][c] + red[1][c] + red[2][c] + red[3][c] + pb1[c]);
    __syncthreads();

    p = 0.f;
#pragma unroll 8
    for (int k = q * 32; k < q * 32 + 32; k++) p += z[k] * pW2[k * H + c];
    red[q][c] = p;
    __syncthreads();
    if (q == 0) row[c] = red[0][c] + red[1][c] + red[2][c] + red[3][c] + pb2[c]
                         + t_emb[g * H + c];
    __syncthreads();

    p = 0.f;
#pragma unroll 8
    for (int k = q * 32; k < q * 32 + 32; k++)
        p += row[k] * npW1[(size_t)(128 + k) * H + c];
    red[q][c] = p;
    __syncthreads();
    if (q == 0) tgW[g * H + c] = red[0][c] + red[1][c] + red[2][c] + red[3][c] + npb1[c];
}

// ---------------------------------------------------------------------------
extern "C" void kernel_launch(void* const* d_in, const int* in_sizes, int n_in,
                              void* d_out, int out_size, void* d_ws, size_t ws_size,
                              hipStream_t stream)
{
    const float* x          = (const float*)d_in[0];
    const int*   edge_index = (const int*)d_in[1];
    const float* edge_attr  = (const float*)d_in[2];
    const int*   batch      = (const int*)d_in[3];
    const int*   t          = (const int*)d_in[4];
    const float* atom_W     = (const float*)d_in[5];
    const float* atom_b     = (const float*)d_in[6];
    const float* bond_W     = (const float*)d_in[7];
    const float* bond_b     = (const float*)d_in[8];
    const float* lin_W      = (const float*)d_in[9];
    const float* edge_W     = (const float*)d_in[10];
    const float* att_src    = (const float*)d_in[11];
    const float* att_dst    = (const float*)d_in[12];
    const float* att_edge   = (const float*)d_in[13];
    const float* conv_b     = (const float*)d_in[14];
    const float* bn_gamma   = (const float*)d_in[15];
    const float* bn_beta    = (const float*)d_in[16];
    const float* out_W      = (const float*)d_in[17];
    const float* out_b      = (const float*)d_in[18];
    const float* time_W1    = (const float*)d_in[19];
    const float* time_b1    = (const float*)d_in[20];
    const float* time_W2    = (const float*)d_in[21];
    const float* time_b2    = (const float*)d_in[22];
    const float* pool_W1    = (const float*)d_in[23];
    const float* pool_b1    = (const float*)d_in[24];
    const float* pool_W2    = (const float*)d_in[25];
    const float* pool_b2    = (const float*)d_in[26];
    const float* np_W1      = (const float*)d_in[27];
    const float* np_b1      = (const float*)d_in[28];
    const float* np_W2      = (const float*)d_in[29];
    const float* np_b2      = (const float*)d_in[30];
    const float* np_W3      = (const float*)d_in[31];
    const float* np_b3      = (const float*)d_in[32];

    // ---------------- workspace layout (floats), total 71.6 MB ----------------
    const size_t OFF_H     = 0;                      // [N*H]
    const size_t OFF_XH    = 6400000;                // [N*H]
    const size_t OFF_AGG   = 12800000;               // [N*HQ] (also pool partials)
    const size_t OFF_ASE   = 16000000;               // half[E][4] = 1.6M floats
    const size_t OFF_SD    = 17600000;               // [N*4]
    const size_t OFF_TEMB  = 17800000;               // [NB*H]
    const size_t OFF_TGW   = 17832768;               // [NB*H]
    const size_t OFF_MC    = 17865536;               // 256
    const size_t OFF_BNSC  = 17865792;               // 128
    const size_t OFF_BNSH  = 17865920;               // 128
    const size_t OFF_PART  = 17866048;               // 32768
    const size_t REQ_FLOATS = 17898816;
    const size_t REQ_BYTES  = REQ_FLOATS * 4;        // 71,595,264 (proven OK)

    if (ws_size < REQ_BYTES) {
        hipMemsetAsync(d_out, 0, (size_t)out_size * sizeof(float), stream);
        return;
    }

    float* fws    = (float*)d_ws;
    float* h      = fws + OFF_H;
    float* xh     = fws + OFF_XH;
    float* agg    = fws + OFF_AGG;
    __half* ase   = (__half*)(fws + OFF_ASE);
    float* sD     = fws + OFF_SD;
    float* t_emb  = fws + OFF_TEMB;
    float* tgW    = fws + OFF_TGW;
    float* mc     = fws + OFF_MC;
    float* bnsc   = fws + OFF_BNSC;
    float* bnsh   = fws + OFF_BNSH;
    float* part   = fws + OFF_PART;
    float* pprt   = agg;   // pool partials (agg dead after GNN loop)

    // d_out scratch (1,950,000 floats): CSR ints + sS.
    int* ib       = (int*)d_out;
    int* csr_ptr  = ib;                    // 50,016
    int2* csr_se  = (int2*)(ib + 50016);   // 800,000 int2
    int* deg      = ib + 1650016;          // 50,016 (hist + scatter cursor)
    int* gptr     = ib + 1700032;          // 260
    int* bsum     = ib + 1700292;          // 64
    int* boff     = ib + 1700356;          // 64
    float* sS     = (float*)d_out + 1700420;  // [N*4] (end 1,900,420)

    hipMemsetAsync(deg, 0, N_NODES * sizeof(int), stream);

    precompute_small<<<1, 256, 0, stream>>>(edge_W, att_edge, bond_W, bond_b, mc);
    time_embed<<<NB, 128, 0, stream>>>(t, time_W1, time_b1, time_W2, time_b2, t_emb);
    gptr_bsearch<<<1, 320, 0, stream>>>(batch, gptr);

    hist_dst<<<(N_EDGES + 255) / 256, 256, 0, stream>>>(edge_index, deg);

    const int GSN = (N_NODES + 1023) / 1024;  // 49
    scan_part<<<GSN, 256, 0, stream>>>(deg, bsum, N_NODES);
    scan_tops<<<1, 256, 0, stream>>>(bsum, boff, GSN, &csr_ptr[N_NODES]);
    scan_final<<<GSN, 256, 0, stream>>>(deg, boff, csr_ptr, N_NODES);

    hipMemsetAsync(deg, 0, N_NODES * sizeof(int), stream);
    scatter_edges<<<(N_EDGES + 255) / 256, 256, 0, stream>>>(edge_index, csr_ptr,
                                                             deg, csr_se);

    const int GB = (N_NODES + 63) / 64;
    const int GE = (N_EDGES + 255) / 256;

    // h = x @ atom_W + atom_b
    gemm128<AD><<<GB, 256, 0, stream>>>(x, atom_W, atom_b, nullptr, nullptr,
                                        h, N_NODES, H, 0,
                                        nullptr, nullptr, nullptr, nullptr);

    for (int l = 0; l < LAYERS; l++) {
        // xh = h @ lin_W[l], fused attention scores sS/sD
        gemm128<H><<<GB, 256, 0, stream>>>(h, lin_W + (size_t)l * H * H, nullptr,
                                           nullptr, nullptr, xh, N_NODES, H, 0,
                                           att_src + l * H, att_dst + l * H, sS, sD);
        ase_csr<<<GE, 256, 0, stream>>>(csr_se, edge_attr, sS, mc + l * 44, ase);
        for (int half = 0; half < 2; half++) {
            int hh0 = half * 2;
            int coff = half * HQ;
            gat_agg_h<<<N_NODES / 4, 256, 0, stream>>>(
                xh, coff, ase, hh0, csr_ptr, csr_se, sD,
                conv_b + l * H + coff, agg);
            bn_partial_h<<<256, 256, 0, stream>>>(agg, part);
            bn_finish_h<<<1, 256, 0, stream>>>(part, bn_gamma + l * H + coff,
                                               bn_beta + l * H + coff, bnsc, bnsh);
            bn_apply_h<<<(N_NODES * HQ / 4 + 255) / 256, 256, 0, stream>>>(
                agg, bnsc, bnsh, h, coff);
        }
    }

    // node_features = h @ out_W + out_b  -> xh
    gemm128<H><<<GB, 256, 0, stream>>>(h, out_W, out_b, nullptr, nullptr,
                                       xh, N_NODES, H, 0,
                                       nullptr, nullptr, nullptr, nullptr);

    // graph pooling + head MLP
    pool_partial<<<NB * 4, 128, 0, stream>>>(xh, gptr, pprt);
    graph_head_mlp<<<NB, 512, 0, stream>>>(gptr, pprt, t_emb, pool_W1, pool_b1,
                                           pool_W2, pool_b2, np_W1, np_b1, tgW);

    // fused z1 -> z2 -> out   (overwrites d_out scratch, now dead)
    np_fused<<<GB, 256, 0, stream>>>(xh, batch, tgW, np_W1, np_W2, np_b2,
                                     np_W3, np_b3, (float*)d_out, N_NODES);
}

// Round 12
// 828.951 us; speedup vs baseline: 1.1171x; 1.1171x over previous
//
#include <hip/hip_runtime.h>
#include <hip/hip_fp16.h>
#include <math.h>

#define N_NODES 50000
#define N_EDGES 800000
#define NB 256
#define AD 39
#define BD 10
#define H 128
#define HQ 64
#define HEADS 4
#define HD 32
#define LAYERS 3
#define TD 128

__device__ __forceinline__ float silu_f(float x) { return x / (1.f + __expf(-x)); }

// ---------------------------------------------------------------------------
// Specialized GEMM: out[N,128] = act(A[N,KT] @ W[KT,128](ldw) + bias
//                                    + bias2[gidx[n]])
// Optional fused attention scores: outS/outD[n][head] = sum_c out[n][c]*att[c]
// ---------------------------------------------------------------------------
__device__ __forceinline__ void fma_rank1(float acc[8][4], float4 aL, float4 aH, float4 w)
{
    float ar[8] = {aL.x, aL.y, aL.z, aL.w, aH.x, aH.y, aH.z, aH.w};
    float wr[4] = {w.x, w.y, w.z, w.w};
#pragma unroll
    for (int r = 0; r < 8; r++)
#pragma unroll
        for (int j = 0; j < 4; j++) acc[r][j] += ar[r] * wr[j];
}

template<int KT>
__global__ __launch_bounds__(256) void gemm128(
    const float* __restrict__ A, const float* __restrict__ W,
    const float* __restrict__ bias, const float* __restrict__ bias2,
    const int* __restrict__ gidx, float* __restrict__ out,
    int Nrows, int ldw, int act,
    const float* __restrict__ attS, const float* __restrict__ attD,
    float* __restrict__ outS, float* __restrict__ outD)
{
    __shared__ float As[KT * 68];
    const int tid = threadIdx.x;
    const int rowBase = blockIdx.x * 64;

    for (int idx = tid; idx < 64 * KT; idx += 256) {
        int row = idx / KT;
        int k = idx - row * KT;
        int n = rowBase + row;
        As[k * 68 + row] = (n < Nrows) ? A[(size_t)n * KT + k] : 0.f;
    }
    __syncthreads();

    const int c0 = (tid & 31) * 4;
    const int n0 = (tid >> 5) * 8;

    float acc[8][4];
#pragma unroll
    for (int r = 0; r < 8; r++)
#pragma unroll
        for (int j = 0; j < 4; j++) acc[r][j] = 0.f;

    const float* wp = W + c0;
    int k = 0;
    for (; k + 4 <= KT; k += 4) {
        float4 w0 = *(const float4*)&wp[(size_t)(k + 0) * ldw];
        float4 w1 = *(const float4*)&wp[(size_t)(k + 1) * ldw];
        float4 w2 = *(const float4*)&wp[(size_t)(k + 2) * ldw];
        float4 w3 = *(const float4*)&wp[(size_t)(k + 3) * ldw];
        float4 aL0 = *(const float4*)&As[(k + 0) * 68 + n0];
        float4 aH0 = *(const float4*)&As[(k + 0) * 68 + n0 + 4];
        float4 aL1 = *(const float4*)&As[(k + 1) * 68 + n0];
        float4 aH1 = *(const float4*)&As[(k + 1) * 68 + n0 + 4];
        float4 aL2 = *(const float4*)&As[(k + 2) * 68 + n0];
        float4 aH2 = *(const float4*)&As[(k + 2) * 68 + n0 + 4];
        float4 aL3 = *(const float4*)&As[(k + 3) * 68 + n0];
        float4 aH3 = *(const float4*)&As[(k + 3) * 68 + n0 + 4];
        fma_rank1(acc, aL0, aH0, w0);
        fma_rank1(acc, aL1, aH1, w1);
        fma_rank1(acc, aL2, aH2, w2);
        fma_rank1(acc, aL3, aH3, w3);
    }
    for (; k < KT; ++k) {
        float4 w0 = *(const float4*)&wp[(size_t)k * ldw];
        float4 aL = *(const float4*)&As[k * 68 + n0];
        float4 aH = *(const float4*)&As[k * 68 + n0 + 4];
        fma_rank1(acc, aL, aH, w0);
    }

    float4 bv = make_float4(0.f, 0.f, 0.f, 0.f);
    if (bias) bv = *(const float4*)&bias[c0];
    float4 aSv = make_float4(0.f, 0.f, 0.f, 0.f);
    float4 aDv = make_float4(0.f, 0.f, 0.f, 0.f);
    if (outS) { aSv = *(const float4*)&attS[c0]; aDv = *(const float4*)&attD[c0]; }

#pragma unroll
    for (int r = 0; r < 8; r++) {
        int n = rowBase + n0 + r;
        if (n >= Nrows) break;   // uniform within each 32-lane group
        float4 o;
        o.x = acc[r][0] + bv.x;
        o.y = acc[r][1] + bv.y;
        o.z = acc[r][2] + bv.z;
        o.w = acc[r][3] + bv.w;
        if (bias2) {
            float4 b2 = *(const float4*)&bias2[(size_t)gidx[n] * H + c0];
            o.x += b2.x; o.y += b2.y; o.z += b2.z; o.w += b2.w;
        }
        if (act) {
            o.x = silu_f(o.x); o.y = silu_f(o.y);
            o.z = silu_f(o.z); o.w = silu_f(o.w);
        }
        *(float4*)&out[(size_t)n * H + c0] = o;
        if (outS) {
            float ps = o.x * aSv.x + o.y * aSv.y + o.z * aSv.z + o.w * aSv.w;
            float pd = o.x * aDv.x + o.y * aDv.y + o.z * aDv.z + o.w * aDv.w;
#pragma unroll
            for (int off = 4; off >= 1; off >>= 1) {
                ps += __shfl_xor(ps, off, 8);
                pd += __shfl_xor(pd, off, 8);
            }
            if ((tid & 7) == 0) {
                int head = (tid & 31) >> 3;
                outS[n * 4 + head] = ps;
                outD[n * 4 + head] = pd;
            }
        }
    }
}

// ---------------------------------------------------------------------------
// Fused noise-prediction head (round-10 variant, measured fastest):
// z1 = silu(nf@W1[0:128] + tgW[batch]); z2 = silu(z1@W2 + b2); out = z2@W3+b3.
// ---------------------------------------------------------------------------
__global__ __launch_bounds__(256) void np_fused(
    const float* __restrict__ nf, const int* __restrict__ batch,
    const float* __restrict__ tgW,
    const float* __restrict__ npW1,
    const float* __restrict__ npW2, const float* __restrict__ npb2,
    const float* __restrict__ npW3, const float* __restrict__ npb3,
    float* __restrict__ out, int Nrows)
{
    __shared__ float As[H * 68];
    const int tid = threadIdx.x;
    const int rowBase = blockIdx.x * 64;
    const int c0 = (tid & 31) * 4;
    const int n0 = (tid >> 5) * 8;

    for (int idx = tid; idx < 64 * H; idx += 256) {
        int row = idx >> 7;
        int k = idx & 127;
        int n = rowBase + row;
        As[k * 68 + row] = (n < Nrows) ? nf[(size_t)n * H + k] : 0.f;
    }
    __syncthreads();

    float acc[8][4];

    // ---- GEMM1: z1 ----
#pragma unroll
    for (int r = 0; r < 8; r++)
#pragma unroll
        for (int j = 0; j < 4; j++) acc[r][j] = 0.f;
    {
        const float* wp = npW1 + c0;
#pragma unroll 4
        for (int k = 0; k < H; k++) {
            float4 w = *(const float4*)&wp[(size_t)k * H];
            float4 aL = *(const float4*)&As[k * 68 + n0];
            float4 aH = *(const float4*)&As[k * 68 + n0 + 4];
            fma_rank1(acc, aL, aH, w);
        }
    }
    __syncthreads();  // all GEMM1 reads done before overwrite
#pragma unroll
    for (int r = 0; r < 8; r++) {
        int n = rowBase + n0 + r;
        const float* tg = (n < Nrows) ? &tgW[(size_t)batch[n] * H] : nullptr;
#pragma unroll
        for (int j = 0; j < 4; j++) {
            float v = acc[r][j] + (tg ? tg[c0 + j] : 0.f);
            As[(c0 + j) * 68 + n0 + r] = silu_f(v);
        }
    }
    __syncthreads();

    // ---- GEMM2: z2 ----
#pragma unroll
    for (int r = 0; r < 8; r++)
#pragma unroll
        for (int j = 0; j < 4; j++) acc[r][j] = 0.f;
    {
        const float* wp = npW2 + c0;
#pragma unroll 4
        for (int k = 0; k < H; k++) {
            float4 w = *(const float4*)&wp[(size_t)k * H];
            float4 aL = *(const float4*)&As[k * 68 + n0];
            float4 aH = *(const float4*)&As[k * 68 + n0 + 4];
            fma_rank1(acc, aL, aH, w);
        }
    }
    __syncthreads();
    {
        float4 b2 = *(const float4*)&npb2[c0];
        float br[4] = {b2.x, b2.y, b2.z, b2.w};
#pragma unroll
        for (int r = 0; r < 8; r++)
#pragma unroll
            for (int j = 0; j < 4; j++)
                As[(c0 + j) * 68 + n0 + r] = silu_f(acc[r][j] + br[j]);
    }
    __syncthreads();

    // ---- GEMM3: out[64,39] ----
    {
        int cg = tid % 10;
        int ng = tid / 10;
        if (ng >= 16) return;
        int cc0 = cg * 4, nn0 = ng * 4;
        float a16[16];
#pragma unroll
        for (int i = 0; i < 16; i++) a16[i] = 0.f;
#pragma unroll 4
        for (int k = 0; k < H; k++) {
            float4 a = *(const float4*)&As[k * 68 + nn0];
            size_t base = (size_t)k * AD + cc0;
            float w0 = npW3[base + 0];
            float w1 = (cc0 + 1 < AD) ? npW3[base + 1] : 0.f;
            float w2 = (cc0 + 2 < AD) ? npW3[base + 2] : 0.f;
            float w3 = (cc0 + 3 < AD) ? npW3[base + 3] : 0.f;
            a16[0]  += a.x * w0; a16[1]  += a.x * w1; a16[2]  += a.x * w2; a16[3]  += a.x * w3;
            a16[4]  += a.y * w0; a16[5]  += a.y * w1; a16[6]  += a.y * w2; a16[7]  += a.y * w3;
            a16[8]  += a.z * w0; a16[9]  += a.z * w1; a16[10] += a.z * w2; a16[11] += a.z * w3;
            a16[12] += a.w * w0; a16[13] += a.w * w1; a16[14] += a.w * w2; a16[15] += a.w * w3;
        }
#pragma unroll
        for (int i = 0; i < 4; i++) {
            int n = rowBase + nn0 + i;
            if (n >= Nrows) continue;
#pragma unroll
            for (int j = 0; j < 4; j++) {
                int c = cc0 + j;
                if (c >= AD) continue;
                out[(size_t)n * AD + c] = a16[i * 4 + j] + npb3[c];
            }
        }
    }
}

// ---------------------------------------------------------------------------
// Fold edge path coefficients
// ---------------------------------------------------------------------------
__global__ __launch_bounds__(256) void precompute_small(
    const float* __restrict__ edge_W, const float* __restrict__ att_edge,
    const float* __restrict__ bond_W, const float* __restrict__ bond_b,
    float* __restrict__ mc)
{
    __shared__ float bl[LAYERS][H][4];
    int tid = threadIdx.x;
    for (int task = tid; task < LAYERS * H; task += 256) {
        int l = task / H, k = task % H;
#pragma unroll
        for (int hh = 0; hh < 4; hh++) {
            float s = 0.f;
            for (int d = 0; d < HD; d++)
                s += edge_W[(size_t)l * H * H + k * H + hh * HD + d] *
                     att_edge[l * H + hh * HD + d];
            bl[l][k][hh] = s;
        }
    }
    __syncthreads();
    if (tid < LAYERS * BD * 4) {
        int l = tid / (BD * 4), r = tid % (BD * 4), j = r / 4, hh = r % 4;
        float s = 0.f;
        for (int k = 0; k < H; k++) s += bond_W[j * H + k] * bl[l][k][hh];
        mc[l * 44 + j * 4 + hh] = s;
    }
    if (tid >= 128 && tid < 128 + LAYERS * 4) {
        int r = tid - 128, l = r / 4, hh = r % 4;
        float s = 0.f;
        for (int k = 0; k < H; k++) s += bond_b[k] * bl[l][k][hh];
        mc[l * 44 + 40 + hh] = s;
    }
}

// ---------------------------------------------------------------------------
__global__ __launch_bounds__(128) void time_embed(
    const int* __restrict__ t,
    const float* __restrict__ W1, const float* __restrict__ b1,
    const float* __restrict__ W2, const float* __restrict__ b2,
    float* __restrict__ t_emb)
{
    int g = blockIdx.x, c = threadIdx.x;
    float tf = (float)t[g];
    __shared__ float emb[TD], z[H];
    int k = c & 63;
    float f = __expf(-9.210340371976184f * (float)k / 63.0f);
    float e = tf * f;
    emb[c] = (c < 64) ? sinf(e) : cosf(e);
    __syncthreads();
    float a1 = b1[c];
    for (int kk = 0; kk < TD; kk++) a1 += emb[kk] * W1[kk * H + c];
    z[c] = silu_f(a1);
    __syncthreads();
    float a2 = b2[c];
    for (int kk = 0; kk < H; kk++) a2 += z[kk] * W2[kk * H + c];
    t_emb[g * H + c] = a2;
}

// ---------------------------------------------------------------------------
// CSR build
// ---------------------------------------------------------------------------
__global__ __launch_bounds__(256) void hist_dst(const int* __restrict__ edge_index,
                                                int* __restrict__ deg)
{
    int e = blockIdx.x * 256 + threadIdx.x;
    if (e < N_EDGES) atomicAdd(&deg[edge_index[N_EDGES + e]], 1);
}

__global__ __launch_bounds__(320) void gptr_bsearch(const int* __restrict__ batch,
                                                    int* __restrict__ gptr)
{
    int g = threadIdx.x;
    if (g > NB) return;
    int lo = 0, hi = N_NODES;
    while (lo < hi) {
        int mid = (lo + hi) >> 1;
        if (batch[mid] < g) lo = mid + 1; else hi = mid;
    }
    gptr[g] = lo;
}

__global__ __launch_bounds__(256) void scan_part(const int* __restrict__ cnt,
                                                 int* __restrict__ bsum, int n)
{
    int tid = threadIdx.x;
    int i0 = blockIdx.x * 1024 + tid * 4;
    int s = 0;
#pragma unroll
    for (int j = 0; j < 4; j++) if (i0 + j < n) s += cnt[i0 + j];
    __shared__ int red[256];
    red[tid] = s;
    __syncthreads();
    for (int off = 128; off >= 1; off >>= 1) {
        if (tid < off) red[tid] += red[tid + off];
        __syncthreads();
    }
    if (tid == 0) bsum[blockIdx.x] = red[0];
}

__global__ __launch_bounds__(256) void scan_tops(const int* __restrict__ bsum,
                                                 int* __restrict__ boff, int G,
                                                 int* __restrict__ total)
{
    int tid = threadIdx.x;
    int v = (tid < G) ? bsum[tid] : 0;
    __shared__ int ps[256];
    ps[tid] = v;
    __syncthreads();
    for (int off = 1; off < 256; off <<= 1) {
        int t = (tid >= off) ? ps[tid - off] : 0;
        __syncthreads();
        ps[tid] += t;
        __syncthreads();
    }
    if (tid < G) boff[tid] = ps[tid] - v;
    if (tid == 255) *total = ps[255];
}

__global__ __launch_bounds__(256) void scan_final(const int* __restrict__ cnt,
                                                  const int* __restrict__ boff,
                                                  int* __restrict__ ptr, int n)
{
    int tid = threadIdx.x;
    int i0 = blockIdx.x * 1024 + tid * 4;
    int v[4];
#pragma unroll
    for (int j = 0; j < 4; j++) v[j] = (i0 + j < n) ? cnt[i0 + j] : 0;
    int s = v[0] + v[1] + v[2] + v[3];
    __shared__ int ps[256];
    ps[tid] = s;
    __syncthreads();
    for (int off = 1; off < 256; off <<= 1) {
        int t = (tid >= off) ? ps[tid - off] : 0;
        __syncthreads();
        ps[tid] += t;
        __syncthreads();
    }
    int run = boff[blockIdx.x] + ps[tid] - s;
#pragma unroll
    for (int j = 0; j < 4; j++) {
        if (i0 + j < n) { ptr[i0 + j] = run; run += v[j]; }
    }
}

// One 8B scattered write per edge: csr_se[p] = {src, e}
__global__ __launch_bounds__(256) void scatter_edges(const int* __restrict__ edge_index,
                                                     const int* __restrict__ ptr,
                                                     int* __restrict__ cursor,
                                                     int2* __restrict__ csr_se)
{
    int e = blockIdx.x * 256 + threadIdx.x;
    if (e >= N_EDGES) return;
    int s = edge_index[e];
    int d = edge_index[N_EDGES + e];
    int pos = atomicAdd(&cursor[d], 1);
    csr_se[ptr[d] + pos] = make_int2(s, e);
}

// ---------------------------------------------------------------------------
// ase[p][hh] = sS[src][hh] + edge_attr[e] @ M_l[:,hh] + c_l[hh]  (pre-leaky)
// ---------------------------------------------------------------------------
__global__ __launch_bounds__(256) void ase_csr(
    const int2* __restrict__ csr_se, const float* __restrict__ edge_attr,
    const float* __restrict__ sS, const float* __restrict__ mc_l,
    __half* __restrict__ ase)
{
    __shared__ float Ml[BD * 4], cl[4];
    int tid = threadIdx.x;
    if (tid < 40) Ml[tid] = mc_l[tid];
    if (tid >= 40 && tid < 44) cl[tid - 40] = mc_l[tid];
    __syncthreads();
    int p = blockIdx.x * 256 + tid;
    if (p >= N_EDGES) return;
    int2 q = csr_se[p];
    float4 ss = *(const float4*)&sS[q.x * 4];
    float s0 = cl[0] + ss.x, s1 = cl[1] + ss.y;
    float s2 = cl[2] + ss.z, s3 = cl[3] + ss.w;
    const float* ea = &edge_attr[(size_t)q.y * BD];
#pragma unroll
    for (int j = 0; j < BD; j++) {
        float x = ea[j];
        s0 += x * Ml[j * 4 + 0]; s1 += x * Ml[j * 4 + 1];
        s2 += x * Ml[j * 4 + 2]; s3 += x * Ml[j * 4 + 3];
    }
    __half2 h01 = __floats2half2_rn(s0, s1);
    __half2 h23 = __floats2half2_rn(s2, s3);
    uint2 u = make_uint2(*(const unsigned*)&h01, *(const unsigned*)&h23);
    *(uint2*)&ase[(size_t)p * 4] = u;
}

// ---------------------------------------------------------------------------
// GAT aggregation, FULL width: one wave per dst node; lane owns 2 channels
// (c0 = lane*2, float2 xh gather = 512B/edge); head = lane>>4 (16-lane group).
// alpha = leaky(ase + sD); invalid edges give exp()=0 -> no masking needed in
// the gather loop.  Output agg as half[N][128].
// ---------------------------------------------------------------------------
__global__ __launch_bounds__(256) void gat_agg_full(
    const float* __restrict__ xh, const __half* __restrict__ ase,
    const int* __restrict__ csr_ptr, const int2* __restrict__ csr_se,
    const float* __restrict__ sD, const float* __restrict__ conv_b_l,
    __half* __restrict__ agg)
{
    int n = (blockIdx.x * 256 + threadIdx.x) >> 6;
    if (n >= N_NODES) return;
    int lane = threadIdx.x & 63;
    int c0 = lane * 2;
    int hd = lane >> 4;
    int start = csr_ptr[n], end = csr_ptr[n + 1];
    float sDn = sD[n * 4 + hd];

    float m_run = -1e30f, d_run = 0.f;
    float acc0 = 0.f, acc1 = 0.f;

    for (int base = start; base < end; base += 64) {
        int cnt = min(64, end - base);
        int s_l = (lane < cnt) ? csr_se[base + lane].x : 0;

        float a_t[4], e_t[4];
        float m_blk = -1e30f;
#pragma unroll
        for (int t = 0; t < 4; t++) {
            int i = (lane & 15) + t * 16;
            float a = -1e30f;
            if (i < cnt) {
                a = __half2float(ase[(size_t)(base + i) * 4 + hd]) + sDn;
                a = (a >= 0.f) ? a : 0.2f * a;
            }
            a_t[t] = a;
            m_blk = fmaxf(m_blk, a);
        }
#pragma unroll
        for (int off = 8; off >= 1; off >>= 1)
            m_blk = fmaxf(m_blk, __shfl_xor(m_blk, off, 16));
        float m_new = fmaxf(m_run, m_blk);
        float rescale = __expf(m_run - m_new);
        float dsum = 0.f;
#pragma unroll
        for (int t = 0; t < 4; t++) {
            e_t[t] = __expf(a_t[t] - m_new);   // 0 for invalid edges
            dsum += e_t[t];
        }
#pragma unroll
        for (int off = 8; off >= 1; off >>= 1)
            dsum += __shfl_xor(dsum, off, 16);
        d_run = d_run * rescale + dsum;
        acc0 *= rescale;
        acc1 *= rescale;

        int srcb = lane & 48;   // own head's 16-lane group base
#pragma unroll
        for (int t = 0; t < 4; t++) {
            int rem = cnt - t * 16;
            if (rem <= 0) break;          // wave-uniform
            int lim = min(16, (rem + 3) & ~3);
            for (int i2 = 0; i2 < lim; i2 += 4) {
                int i = t * 16 + i2;
                int s0 = __shfl(s_l, i + 0), s1 = __shfl(s_l, i + 1);
                int s2 = __shfl(s_l, i + 2), s3 = __shfl(s_l, i + 3);
                float w0 = __shfl(e_t[t], srcb | (i2 + 0));
                float w1 = __shfl(e_t[t], srcb | (i2 + 1));
                float w2 = __shfl(e_t[t], srcb | (i2 + 2));
                float w3 = __shfl(e_t[t], srcb | (i2 + 3));
                float2 x0 = *(const float2*)&xh[(size_t)s0 * H + c0];
                float2 x1 = *(const float2*)&xh[(size_t)s1 * H + c0];
                float2 x2 = *(const float2*)&xh[(size_t)s2 * H + c0];
                float2 x3 = *(const float2*)&xh[(size_t)s3 * H + c0];
                acc0 += x0.x * w0 + x1.x * w1 + x2.x * w2 + x3.x * w3;
                acc1 += x0.y * w0 + x1.y * w1 + x2.y * w2 + x3.y * w3;
            }
        }
        m_run = m_new;
    }
    float inv = 1.f / (d_run + 1e-16f);
    __half2 o = __floats2half2_rn(acc0 * inv + conv_b_l[c0],
                                  acc1 * inv + conv_b_l[c0 + 1]);
    *(__half2*)&agg[(size_t)n * H + c0] = o;
}

// ---------------------------------------------------------------------------
// BatchNorm, full width (agg is half[N][128]); 128 partial blocks.
// ---------------------------------------------------------------------------
__global__ __launch_bounds__(256) void bn_partial_f(const __half* __restrict__ agg,
                                                    float* __restrict__ part)
{
    __shared__ float red[2][2][128];
    int b = blockIdx.x;   // 128 blocks
    int c = threadIdx.x & 127;
    int q = threadIdx.x >> 7;  // 2 row-halves
    int per = (N_NODES + 127) / 128;
    int s = b * per, e = min(N_NODES, s + per);
    int hl = (per + 1) / 2;
    int qs = s + q * hl;
    int qe = min(e, qs + hl);
    float sum = 0.f, sq = 0.f;
    for (int n = qs; n < qe; n++) {
        float v = __half2float(agg[(size_t)n * H + c]);
        sum += v; sq += v * v;
    }
    red[0][q][c] = sum;
    red[1][q][c] = sq;
    __syncthreads();
    if (q == 0) {
        sum = red[0][0][c] + red[0][1][c];
        sq  = red[1][0][c] + red[1][1][c];
        part[b * H + c] = sum;
        part[128 * H + b * H + c] = sq;
    }
}

__global__ __launch_bounds__(256) void bn_finish_f(const float* __restrict__ part,
                                                   const float* __restrict__ gamma,
                                                   const float* __restrict__ beta,
                                                   float* __restrict__ scale,
                                                   float* __restrict__ shift)
{
    __shared__ double red[2][2][128];
    int c = threadIdx.x & 127;
    int g = threadIdx.x >> 7;
    double s = 0.0, q = 0.0;
    for (int b = g * 64; b < (g + 1) * 64; b++) {
        s += (double)part[b * H + c];
        q += (double)part[128 * H + b * H + c];
    }
    red[0][g][c] = s;
    red[1][g][c] = q;
    __syncthreads();
    if (g == 0) {
        s = red[0][0][c] + red[0][1][c];
        q = red[1][0][c] + red[1][1][c];
        float mu = (float)(s / N_NODES);
        float var = (float)(q / N_NODES) - mu * mu;
        float rstd = rsqrtf(var + 1e-5f);
        float sc = gamma[c] * rstd;
        scale[c] = sc;
        shift[c] = beta[c] - mu * sc;
    }
}

__global__ __launch_bounds__(256) void bn_apply_f(const __half* __restrict__ agg,
                                                  const float* __restrict__ scale,
                                                  const float* __restrict__ shift,
                                                  float* __restrict__ h)
{
    int i = blockIdx.x * 256 + threadIdx.x;   // over N*H/4
    if (i >= N_NODES * H / 4) return;
    int n = i >> 5;
    int c0 = (i & 31) * 4;
    uint2 u = *(const uint2*)&agg[(size_t)n * H + c0];
    __half2 h01 = *(__half2*)&u.x;
    __half2 h23 = *(__half2*)&u.y;
    float2 v01 = __half22float2(h01);
    float2 v23 = __half22float2(h23);
    float4 sc = *(const float4*)&scale[c0];
    float4 sh = *(const float4*)&shift[c0];
    float* hp = &h[(size_t)n * H + c0];
    float4 hv = *(const float4*)hp;
    float4 o;
    o.x = fmaxf(v01.x * sc.x + sh.x, 0.f) + hv.x;
    o.y = fmaxf(v01.y * sc.y + sh.y, 0.f) + hv.y;
    o.z = fmaxf(v23.x * sc.z + sh.z, 0.f) + hv.z;
    o.w = fmaxf(v23.y * sc.w + sh.w, 0.f) + hv.w;
    *(float4*)hp = o;
}

// ---------------------------------------------------------------------------
// Graph pooling, stage 1
// ---------------------------------------------------------------------------
__global__ __launch_bounds__(128) void pool_partial(
    const float* __restrict__ nf, const int* __restrict__ gptr,
    float* __restrict__ pprt)
{
    int g = blockIdx.x >> 2;
    int q = blockIdx.x & 3;
    int c = threadIdx.x;
    int s = gptr[g], e = gptr[g + 1];
    int qlen = (e - s + 3) >> 2;
    int qs = s + q * qlen;
    int qe = min(e, qs + qlen);
    float sum = 0.f;
    for (int n = qs; n < qe; n++) sum += nf[(size_t)n * H + c];
    pprt[((size_t)g * 4 + q) * H + c] = sum;
}

// ---------------------------------------------------------------------------
// Graph head MLP
// ---------------------------------------------------------------------------
__global__ __launch_bounds__(512) void graph_head_mlp(
    const int* __restrict__ gptr, const float* __restrict__ pprt,
    const float* __restrict__ t_emb,
    const float* __restrict__ pW1, const float* __restrict__ pb1,
    const float* __restrict__ pW2, const float* __restrict__ pb2,
    const float* __restrict__ npW1, const float* __restrict__ npb1,
    float* __restrict__ tgW)
{
    int g = blockIdx.x;
    int c = threadIdx.x & 127;
    int q = threadIdx.x >> 7;
    __shared__ float row[H], z[H];
    __shared__ float red[4][H];

    int s = gptr[g], e = gptr[g + 1];
    float cf = (e - s > 0) ? (float)(e - s) : 1.f;
    if (q == 0) {
        row[c] = (pprt[((size_t)g * 4 + 0) * H + c] +
                  pprt[((size_t)g * 4 + 1) * H + c] +
                  pprt[((size_t)g * 4 + 2) * H + c] +
                  pprt[((size_t)g * 4 + 3) * H + c]) / cf;
    }
    __syncthreads();

    float p = 0.f;
#pragma unroll 8
    for (int k = q * 32; k < q * 32 + 32; k++) p += row[k] * pW1[k * H + c];
    red[q][c] = p;
    __syncthreads();
    if (q == 0) z[c] = silu_f(red[0][c] + red[1][c] + red[2][c] + red[3][c] + pb1[c]);
    __syncthreads();

    p = 0.f;
#pragma unroll 8
    for (int k = q * 32; k < q * 32 + 32; k++) p += z[k] * pW2[k * H + c];
    red[q][c] = p;
    __syncthreads();
    if (q == 0) row[c] = red[0][c] + red[1][c] + red[2][c] + red[3][c] + pb2[c]
                         + t_emb[g * H + c];
    __syncthreads();

    p = 0.f;
#pragma unroll 8
    for (int k = q * 32; k < q * 32 + 32; k++)
        p += row[k] * npW1[(size_t)(128 + k) * H + c];
    red[q][c] = p;
    __syncthreads();
    if (q == 0) tgW[g * H + c] = red[0][c] + red[1][c] + red[2][c] + red[3][c] + npb1[c];
}

// ---------------------------------------------------------------------------
extern "C" void kernel_launch(void* const* d_in, const int* in_sizes, int n_in,
                              void* d_out, int out_size, void* d_ws, size_t ws_size,
                              hipStream_t stream)
{
    const float* x          = (const float*)d_in[0];
    const int*   edge_index = (const int*)d_in[1];
    const float* edge_attr  = (const float*)d_in[2];
    const int*   batch      = (const int*)d_in[3];
    const int*   t          = (const int*)d_in[4];
    const float* atom_W     = (const float*)d_in[5];
    const float* atom_b     = (const float*)d_in[6];
    const float* bond_W     = (const float*)d_in[7];
    const float* bond_b     = (const float*)d_in[8];
    const float* lin_W      = (const float*)d_in[9];
    const float* edge_W     = (const float*)d_in[10];
    const float* att_src    = (const float*)d_in[11];
    const float* att_dst    = (const float*)d_in[12];
    const float* att_edge   = (const float*)d_in[13];
    const float* conv_b     = (const float*)d_in[14];
    const float* bn_gamma   = (const float*)d_in[15];
    const float* bn_beta    = (const float*)d_in[16];
    const float* out_W      = (const float*)d_in[17];
    const float* out_b      = (const float*)d_in[18];
    const float* time_W1    = (const float*)d_in[19];
    const float* time_b1    = (const float*)d_in[20];
    const float* time_W2    = (const float*)d_in[21];
    const float* time_b2    = (const float*)d_in[22];
    const float* pool_W1    = (const float*)d_in[23];
    const float* pool_b1    = (const float*)d_in[24];
    const float* pool_W2    = (const float*)d_in[25];
    const float* pool_b2    = (const float*)d_in[26];
    const float* np_W1      = (const float*)d_in[27];
    const float* np_b1      = (const float*)d_in[28];
    const float* np_W2      = (const float*)d_in[29];
    const float* np_b2      = (const float*)d_in[30];
    const float* np_W3      = (const float*)d_in[31];
    const float* np_b3      = (const float*)d_in[32];

    // ---------------- workspace layout (floats), total 71.6 MB ----------------
    const size_t OFF_H     = 0;                      // [N*H] fp32
    const size_t OFF_XH    = 6400000;                // [N*H] fp32
    const size_t OFF_AGG   = 12800000;               // half[N][128] = 3.2M floats
    const size_t OFF_ASE   = 16000000;               // half[E][4] = 1.6M floats
    const size_t OFF_SD    = 17600000;               // [N*4]
    const size_t OFF_TEMB  = 17800000;               // [NB*H]
    const size_t OFF_TGW   = 17832768;               // [NB*H]
    const size_t OFF_MC    = 17865536;               // 256
    const size_t OFF_BNSC  = 17865792;               // 128
    const size_t OFF_BNSH  = 17865920;               // 128
    const size_t OFF_PART  = 17866048;               // 128*H*2 = 32768
    const size_t REQ_FLOATS = 17898816;
    const size_t REQ_BYTES  = REQ_FLOATS * 4;        // 71,595,264 (proven OK)

    if (ws_size < REQ_BYTES) {
        hipMemsetAsync(d_out, 0, (size_t)out_size * sizeof(float), stream);
        return;
    }

    float* fws    = (float*)d_ws;
    float* h      = fws + OFF_H;
    float* xh     = fws + OFF_XH;
    __half* agg   = (__half*)(fws + OFF_AGG);
    __half* ase   = (__half*)(fws + OFF_ASE);
    float* sD     = fws + OFF_SD;
    float* t_emb  = fws + OFF_TEMB;
    float* tgW    = fws + OFF_TGW;
    float* mc     = fws + OFF_MC;
    float* bnsc   = fws + OFF_BNSC;
    float* bnsh   = fws + OFF_BNSH;
    float* part   = fws + OFF_PART;
    float* pprt   = fws + OFF_AGG;   // pool partials (agg dead after GNN loop)

    // d_out scratch (1,950,000 floats): CSR ints + sS.
    int* ib       = (int*)d_out;
    int* csr_ptr  = ib;                    // 50,016
    int2* csr_se  = (int2*)(ib + 50016);   // 800,000 int2
    int* deg      = ib + 1650016;          // 50,016 (hist + scatter cursor)
    int* gptr     = ib + 1700032;          // 260
    int* bsum     = ib + 1700292;          // 64
    int* boff     = ib + 1700356;          // 64
    float* sS     = (float*)d_out + 1700420;  // [N*4] (end 1,900,420)

    hipMemsetAsync(deg, 0, N_NODES * sizeof(int), stream);

    precompute_small<<<1, 256, 0, stream>>>(edge_W, att_edge, bond_W, bond_b, mc);
    time_embed<<<NB, 128, 0, stream>>>(t, time_W1, time_b1, time_W2, time_b2, t_emb);
    gptr_bsearch<<<1, 320, 0, stream>>>(batch, gptr);

    hist_dst<<<(N_EDGES + 255) / 256, 256, 0, stream>>>(edge_index, deg);

    const int GSN = (N_NODES + 1023) / 1024;  // 49
    scan_part<<<GSN, 256, 0, stream>>>(deg, bsum, N_NODES);
    scan_tops<<<1, 256, 0, stream>>>(bsum, boff, GSN, &csr_ptr[N_NODES]);
    scan_final<<<GSN, 256, 0, stream>>>(deg, boff, csr_ptr, N_NODES);

    hipMemsetAsync(deg, 0, N_NODES * sizeof(int), stream);
    scatter_edges<<<(N_EDGES + 255) / 256, 256, 0, stream>>>(edge_index, csr_ptr,
                                                             deg, csr_se);

    const int GB = (N_NODES + 63) / 64;
    const int GE = (N_EDGES + 255) / 256;

    // h = x @ atom_W + atom_b
    gemm128<AD><<<GB, 256, 0, stream>>>(x, atom_W, atom_b, nullptr, nullptr,
                                        h, N_NODES, H, 0,
                                        nullptr, nullptr, nullptr, nullptr);

    for (int l = 0; l < LAYERS; l++) {
        // xh = h @ lin_W[l], fused attention scores sS/sD
        gemm128<H><<<GB, 256, 0, stream>>>(h, lin_W + (size_t)l * H * H, nullptr,
                                           nullptr, nullptr, xh, N_NODES, H, 0,
                                           att_src + l * H, att_dst + l * H, sS, sD);
        ase_csr<<<GE, 256, 0, stream>>>(csr_se, edge_attr, sS, mc + l * 44, ase);
        gat_agg_full<<<N_NODES / 4, 256, 0, stream>>>(
            xh, ase, csr_ptr, csr_se, sD, conv_b + l * H, agg);
        bn_partial_f<<<128, 256, 0, stream>>>(agg, part);
        bn_finish_f<<<1, 256, 0, stream>>>(part, bn_gamma + l * H,
                                           bn_beta + l * H, bnsc, bnsh);
        bn_apply_f<<<(N_NODES * H / 4 + 255) / 256, 256, 0, stream>>>(
            agg, bnsc, bnsh, h);
    }

    // node_features = h @ out_W + out_b  -> xh
    gemm128<H><<<GB, 256, 0, stream>>>(h, out_W, out_b, nullptr, nullptr,
                                       xh, N_NODES, H, 0,
                                       nullptr, nullptr, nullptr, nullptr);

    // graph pooling + head MLP
    pool_partial<<<NB * 4, 128, 0, stream>>>(xh, gptr, pprt);
    graph_head_mlp<<<NB, 512, 0, stream>>>(gptr, pprt, t_emb, pool_W1, pool_b1,
                                           pool_W2, pool_b2, np_W1, np_b1, tgW);

    // fused z1 -> z2 -> out   (overwrites d_out scratch, now dead)
    np_fused<<<GB, 256, 0, stream>>>(xh, batch, tgW, np_W1, np_W2, np_b2,
                                     np_W3, np_b3, (float*)d_out, N_NODES);
}